// Round 1
// baseline (10933.232 us; speedup 1.0000x reference)
//
#include <hip/hip_runtime.h>
#include <hip/hip_bf16.h>
#include <math.h>

constexpr int B_   = 2;
constexpr int SEQ  = 2048;
constexpr int HID  = 4096;
constexpr int NH   = 32;
constexpr int HD   = 128;
constexpr float SCALE = 0.08838834764831845f;  // 128^-0.5

// ---------------------------------------------------------------------------
// Tiled fp32 GEMM: C = A(MxK) @ Bm(KxN), 128x128 tile, BK=16, 256 thr, 8x8/thr
// MODE 0: +bias, scatter into Q/K/V buffers laid out [B*NH][SEQ][HD]
// MODE 1: plain row-major store
// ---------------------------------------------------------------------------
template<int MODE>
__global__ __launch_bounds__(256) void gemm128(const float* __restrict__ A,
                                               const float* __restrict__ Bm,
                                               const float* __restrict__ bias,
                                               float* __restrict__ out,
                                               int M, int N, int K) {
  __shared__ float As[16][132];   // A^T staging, padded (132*4B = 16B-aligned rows, conflict-light)
  __shared__ float Bs[16][128];
  const int tid = threadIdx.x;
  const int tx = tid & 15, ty = tid >> 4;
  const int m0 = blockIdx.y * 128, n0 = blockIdx.x * 128;
  float acc[8][8];
  #pragma unroll
  for (int i = 0; i < 8; ++i)
    #pragma unroll
    for (int j = 0; j < 8; ++j) acc[i][j] = 0.f;

  for (int k0 = 0; k0 < K; k0 += 16) {
    __syncthreads();  // protect previous iteration's LDS reads
    // A tile: 128 rows x 16 k  (512 float4, 2 per thread), store transposed
    #pragma unroll
    for (int l = 0; l < 2; ++l) {
      int idx = tid + l * 256;
      int rr = idx >> 2, kq = idx & 3;
      float4 a4 = *(const float4*)(A + (size_t)(m0 + rr) * K + k0 + 4 * kq);
      As[4*kq+0][rr] = a4.x; As[4*kq+1][rr] = a4.y;
      As[4*kq+2][rr] = a4.z; As[4*kq+3][rr] = a4.w;
    }
    // B tile: 16 k x 128 n (512 float4, 2 per thread)
    #pragma unroll
    for (int l = 0; l < 2; ++l) {
      int idx = tid + l * 256;
      int kk = idx >> 5, nq = idx & 31;
      *(float4*)(&Bs[kk][4*nq]) =
          *(const float4*)(Bm + (size_t)(k0 + kk) * N + n0 + 4 * nq);
    }
    __syncthreads();
    #pragma unroll
    for (int kk = 0; kk < 16; ++kk) {
      float a[8], b[8];
      *(float4*)(a)     = *(const float4*)(&As[kk][8*ty]);
      *(float4*)(a + 4) = *(const float4*)(&As[kk][8*ty + 4]);
      *(float4*)(b)     = *(const float4*)(&Bs[kk][8*tx]);
      *(float4*)(b + 4) = *(const float4*)(&Bs[kk][8*tx + 4]);
      #pragma unroll
      for (int i = 0; i < 8; ++i)
        #pragma unroll
        for (int j = 0; j < 8; ++j)
          acc[i][j] = fmaf(a[i], b[j], acc[i][j]);
    }
  }

  if (MODE == 0) {
    // tile is 128 cols wide -> exactly one head of one of q/k/v
    const int which = n0 >> 12;            // 0=q 1=k 2=v
    const int h     = (n0 & 4095) >> 7;
    float* dst0 = out + (size_t)which * ((size_t)B_ * NH * SEQ * HD);
    float bj[8];
    #pragma unroll
    for (int j = 0; j < 8; ++j) bj[j] = bias[n0 + 8*tx + j];
    #pragma unroll
    for (int i = 0; i < 8; ++i) {
      int t = m0 + 8*ty + i;
      int b = t >> 11, s = t & 2047;
      float* dst = dst0 + ((size_t)(b * NH + h) * SEQ + s) * HD + 8*tx;
      *(float4*)(dst)     = make_float4(acc[i][0]+bj[0], acc[i][1]+bj[1],
                                        acc[i][2]+bj[2], acc[i][3]+bj[3]);
      *(float4*)(dst + 4) = make_float4(acc[i][4]+bj[4], acc[i][5]+bj[5],
                                        acc[i][6]+bj[6], acc[i][7]+bj[7]);
    }
  } else {
    #pragma unroll
    for (int i = 0; i < 8; ++i) {
      int t = m0 + 8*ty + i;
      float* dst = out + (size_t)t * N + n0 + 8*tx;
      *(float4*)(dst)     = make_float4(acc[i][0], acc[i][1], acc[i][2], acc[i][3]);
      *(float4*)(dst + 4) = make_float4(acc[i][4], acc[i][5], acc[i][6], acc[i][7]);
    }
  }
}

// ---------------------------------------------------------------------------
// In-place NeoX RoPE on Q and K ([B*NH][SEQ][HD]); Q also folded with SCALE.
// One thread per (tensor, bh, s, d<64) pair: 2^24 threads.
// ---------------------------------------------------------------------------
__global__ __launch_bounds__(256) void rope_kernel(float* __restrict__ qbuf,
                                                   float* __restrict__ kbuf,
                                                   const int* __restrict__ positions) {
  int idx = blockIdx.x * 256 + threadIdx.x;
  int d      = idx & 63;
  int s      = (idx >> 6) & 2047;
  int bh     = (idx >> 17) & 63;
  int tensor = idx >> 23;
  float* base = (tensor == 0 ? qbuf : kbuf) + ((size_t)bh * SEQ + s) * HD;
  int pos = positions[(bh >> 5) * SEQ + s];
  float invf = powf(10000.0f, -(float)d * (1.0f / 64.0f));
  float ang = (float)pos * invf;
  float sn, cs;
  sincosf(ang, &sn, &cs);
  float x1 = base[d], x2 = base[d + 64];
  float y1 = x1 * cs - x2 * sn;
  float y2 = x2 * cs + x1 * sn;
  if (tensor == 0) { y1 *= SCALE; y2 *= SCALE; }
  base[d]      = y1;
  base[d + 64] = y2;
}

// ---------------------------------------------------------------------------
// fp32 causal flash attention. Grid: (SEQ/QBLK, B*NH). 256 threads.
// thread (r=tid/16, g=tid%15): scores for row r, cols {g,g+16,g+32,g+48};
// output slots d = 8g..8g+7.
// ---------------------------------------------------------------------------
__global__ __launch_bounds__(256) void attn_kernel(const float* __restrict__ Q,
                                                   const float* __restrict__ K,
                                                   const float* __restrict__ V,
                                                   float* __restrict__ Out) {
  constexpr int QBLK = 16, KVBLK = 64, KP = 132;
  __shared__ float q_lds[QBLK][KP];
  __shared__ float k_lds[KVBLK][KP];
  __shared__ float v_lds[KVBLK][KP];
  __shared__ float p_lds[QBLK][KVBLK];
  const int tid = threadIdx.x;
  const int r = tid >> 4, g = tid & 15;
  const int qs = blockIdx.x * QBLK;
  const int bh = blockIdx.y;
  const float* Qb = Q + (size_t)bh * SEQ * HD;
  const float* Kb = K + (size_t)bh * SEQ * HD;
  const float* Vb = V + (size_t)bh * SEQ * HD;

  #pragma unroll
  for (int l = 0; l < 2; ++l) {
    int idx = tid + l * 256;
    int rr = idx >> 5, dq = idx & 31;
    *(float4*)(&q_lds[rr][4*dq]) = *(const float4*)(Qb + (size_t)(qs + rr) * HD + 4*dq);
  }

  float m = -INFINITY, lsum = 0.f;
  float o[8] = {0, 0, 0, 0, 0, 0, 0, 0};
  const int qrow = qs + r;
  const int nt = (qs + QBLK + KVBLK - 1) / KVBLK;

  for (int jt = 0; jt < nt; ++jt) {
    const int j0 = jt * KVBLK;
    __syncthreads();
    #pragma unroll
    for (int l = 0; l < 8; ++l) {
      int idx = tid + l * 256;
      int rr = idx >> 5, dq = idx & 31;
      *(float4*)(&k_lds[rr][4*dq]) = *(const float4*)(Kb + (size_t)(j0 + rr) * HD + 4*dq);
      *(float4*)(&v_lds[rr][4*dq]) = *(const float4*)(Vb + (size_t)(j0 + rr) * HD + 4*dq);
    }
    __syncthreads();

    float sc[4] = {0, 0, 0, 0};
    for (int dq = 0; dq < 32; ++dq) {
      float4 qv = *(const float4*)(&q_lds[r][4*dq]);
      #pragma unroll
      for (int cc = 0; cc < 4; ++cc) {
        const int c = g + 16 * cc;
        float4 kv = *(const float4*)(&k_lds[c][4*dq]);
        sc[cc] = fmaf(qv.x, kv.x, sc[cc]);
        sc[cc] = fmaf(qv.y, kv.y, sc[cc]);
        sc[cc] = fmaf(qv.z, kv.z, sc[cc]);
        sc[cc] = fmaf(qv.w, kv.w, sc[cc]);
      }
    }

    float tmax = -INFINITY;
    #pragma unroll
    for (int cc = 0; cc < 4; ++cc) {
      if (j0 + g + 16 * cc > qrow) sc[cc] = -INFINITY;  // causal mask
      tmax = fmaxf(tmax, sc[cc]);
    }
    #pragma unroll
    for (int off = 1; off < 16; off <<= 1)
      tmax = fmaxf(tmax, __shfl_xor(tmax, off));
    const float mnew = fmaxf(m, tmax);           // finite from tile 0 on
    const float rescale = __expf(m - mnew);      // exp(-inf)=0 on first tile
    float psum = 0.f;
    #pragma unroll
    for (int cc = 0; cc < 4; ++cc) {
      float p = __expf(sc[cc] - mnew);           // masked -> 0
      p_lds[r][g + 16 * cc] = p;                 // same-wave row group: no barrier needed
      psum += p;
    }
    #pragma unroll
    for (int off = 1; off < 16; off <<= 1)
      psum += __shfl_xor(psum, off);
    lsum = lsum * rescale + psum;
    m = mnew;
    #pragma unroll
    for (int k = 0; k < 8; ++k) o[k] *= rescale;

    for (int c = 0; c < KVBLK; ++c) {
      const float p = p_lds[r][c];
      float4 va  = *(const float4*)(&v_lds[c][8*g]);
      float4 vb4 = *(const float4*)(&v_lds[c][8*g + 4]);
      o[0] = fmaf(p, va.x,  o[0]); o[1] = fmaf(p, va.y,  o[1]);
      o[2] = fmaf(p, va.z,  o[2]); o[3] = fmaf(p, va.w,  o[3]);
      o[4] = fmaf(p, vb4.x, o[4]); o[5] = fmaf(p, vb4.y, o[5]);
      o[6] = fmaf(p, vb4.z, o[6]); o[7] = fmaf(p, vb4.w, o[7]);
    }
  }

  const float inv = 1.0f / lsum;
  const int b = bh >> 5, h = bh & 31;
  float* dst = Out + ((size_t)(b * SEQ + qrow)) * HID + h * HD + 8 * g;
  *(float4*)(dst)     = make_float4(o[0]*inv, o[1]*inv, o[2]*inv, o[3]*inv);
  *(float4*)(dst + 4) = make_float4(o[4]*inv, o[5]*inv, o[6]*inv, o[7]*inv);
}

// ---------------------------------------------------------------------------
extern "C" void kernel_launch(void* const* d_in, const int* in_sizes, int n_in,
                              void* d_out, int out_size, void* d_ws, size_t ws_size,
                              hipStream_t stream) {
  const int*   positions = (const int*)d_in[0];
  const float* hidden    = (const float*)d_in[1];
  const float* w_qkv     = (const float*)d_in[2];
  const float* b_qkv     = (const float*)d_in[3];
  const float* w_proj    = (const float*)d_in[4];
  float* out = (float*)d_out;

  float* ws   = (float*)d_ws;
  const size_t TEN = (size_t)B_ * NH * SEQ * HD;   // 16,777,216
  float* qb   = ws;                 // [B*NH][SEQ][HD] fp32, roped+scaled
  float* kb   = ws + TEN;           // roped
  float* vb   = ws + 2 * TEN;
  float* attn = ws + 3 * TEN;       // [B*SEQ][HID]

  // 1) QKV GEMM + bias, scattered to q/k/v layouts
  gemm128<0><<<dim3(96, 32), 256, 0, stream>>>(hidden, w_qkv, b_qkv, ws,
                                               4096, 3 * HID, HID);
  // 2) RoPE (in-place) + fold softmax scale into Q
  rope_kernel<<<65536, 256, 0, stream>>>(qb, kb, positions);
  // 3) causal flash attention
  attn_kernel<<<dim3(SEQ / 16, B_ * NH), 256, 0, stream>>>(qb, kb, vb, attn);
  // 4) output projection
  gemm128<1><<<dim3(32, 32), 256, 0, stream>>>(attn, w_proj, nullptr, out,
                                               4096, HID, HID);
}

// Round 3
// 5319.987 us; speedup vs baseline: 2.0551x; 2.0551x over previous
//
#include <hip/hip_runtime.h>
#include <hip/hip_bf16.h>
#include <math.h>

constexpr int B_   = 2;
constexpr int SEQ  = 2048;
constexpr int HID  = 4096;
constexpr int NH   = 32;
constexpr int HD   = 128;
constexpr float SCALE = 0.08838834764831845f;  // 128^-0.5
constexpr size_t TEN = (size_t)B_ * NH * SEQ * HD;  // 16,777,216 per tensor

typedef __attribute__((ext_vector_type(8))) __bf16 bf16x8;
typedef __attribute__((ext_vector_type(4))) float f32x4;

__device__ __forceinline__ ushort f2bf(float f) {  // RNE fp32->bf16
  uint u = __float_as_uint(f);
  return (ushort)((u + 0x7fffu + ((u >> 16) & 1u)) >> 16);
}
__device__ __forceinline__ float bfl(uint u) { return __uint_as_float(u << 16); }

__device__ __forceinline__ void gload16(const void* g, void* l) {
  __builtin_amdgcn_global_load_lds((__attribute__((address_space(1))) void*)(g),
                                   (__attribute__((address_space(3))) void*)(l),
                                   16, 0, 0);
}

#define UNPK8(raw, qp) {                                                              \
  (qp)[0]=__uint_as_float((raw).x<<16); (qp)[1]=__uint_as_float((raw).x&0xffff0000u); \
  (qp)[2]=__uint_as_float((raw).y<<16); (qp)[3]=__uint_as_float((raw).y&0xffff0000u); \
  (qp)[4]=__uint_as_float((raw).z<<16); (qp)[5]=__uint_as_float((raw).z&0xffff0000u); \
  (qp)[6]=__uint_as_float((raw).w<<16); (qp)[7]=__uint_as_float((raw).w&0xffff0000u); }

// ---------------------------------------------------------------------------
// fp32 -> bf16 straight convert (n divisible by 2048)
// ---------------------------------------------------------------------------
__global__ __launch_bounds__(256) void conv_bf16(const float* __restrict__ in,
                                                 ushort* __restrict__ out) {
  const size_t i = ((size_t)blockIdx.x * 256 + threadIdx.x) * 8;
  float4 x = *(const float4*)(in + i);
  float4 y = *(const float4*)(in + i + 4);
  uint4 pk;
  pk.x = (uint)f2bf(x.x) | ((uint)f2bf(x.y) << 16);
  pk.y = (uint)f2bf(x.z) | ((uint)f2bf(x.w) << 16);
  pk.z = (uint)f2bf(y.x) | ((uint)f2bf(y.y) << 16);
  pk.w = (uint)f2bf(y.z) | ((uint)f2bf(y.w) << 16);
  *(uint4*)(out + i) = pk;
}

// ---------------------------------------------------------------------------
// transpose + convert: in [R][C] fp32 -> out [C][R] bf16  (R,C mult of 32)
// ---------------------------------------------------------------------------
__global__ __launch_bounds__(256) void transp_bf16(const float* __restrict__ in,
                                                   ushort* __restrict__ out,
                                                   int R, int C) {
  __shared__ float t[32][33];
  const int tx = threadIdx.x & 31, ty = threadIdx.x >> 5;
  const int c0 = blockIdx.x * 32, r0 = blockIdx.y * 32;
  #pragma unroll
  for (int i = 0; i < 4; ++i)
    t[ty + 8*i][tx] = in[(size_t)(r0 + ty + 8*i) * C + c0 + tx];
  __syncthreads();
  #pragma unroll
  for (int i = 0; i < 4; ++i)
    out[(size_t)(c0 + ty + 8*i) * R + r0 + tx] = f2bf(t[tx][ty + 8*i]);
}

// ---------------------------------------------------------------------------
// bf16 MFMA GEMM, m97 structure: C = A(MxK) @ Bt(NxK)^T.  128x128 tile, BK=32,
// 4 waves (2x2), 4x4 frags of 16x16x32 per wave, global_load_lds width=16.
// MODE 0: +bias, scatter bf16 into q/k/v [B*NH][SEQ][HD] (outp = q base)
// MODE 1: plain fp32 row-major store
// ---------------------------------------------------------------------------
template<int MODE>
__global__ __launch_bounds__(256) void gemm_mfma(const ushort* __restrict__ A,
                                                 const ushort* __restrict__ Bt,
                                                 const float* __restrict__ bias,
                                                 void* __restrict__ outp,
                                                 int N, int K) {
  __shared__ __align__(16) ushort As[128 * 32];
  __shared__ __align__(16) ushort Bs[128 * 32];
  const int tid = threadIdx.x;
  const int wave = tid >> 6, lane = tid & 63;
  const int wr = wave >> 1, wc = wave & 1;
  const int m0 = blockIdx.y * 128, n0 = blockIdx.x * 128;

  f32x4 acc[4][4];
  #pragma unroll
  for (int i = 0; i < 4; ++i)
    #pragma unroll
    for (int j = 0; j < 4; ++j) acc[i][j] = (f32x4){0.f, 0.f, 0.f, 0.f};

  // staging: wave covers 32 rows of each tile; 2 calls x 64 lanes x 16B
  const int srow = 32 * wave + (lane >> 2);
  const int skq8 = (lane & 3) * 8;
  const ushort* Ag0 = A  + (size_t)(m0 + srow) * K + skq8;
  const ushort* Bg0 = Bt + (size_t)(n0 + srow) * K + skq8;
  char* AsB = (char*)As + wave * 2048;
  char* BsB = (char*)Bs + wave * 2048;

  // fragment read addresses: lane l -> row l&15, k-offset (l>>4)*8
  const int fl  = lane & 15;
  const int kh8 = (lane >> 4) * 8;
  const ushort* Ar = As + (wr * 64 + fl) * 32 + kh8;
  const ushort* Br = Bs + (wc * 64 + fl) * 32 + kh8;

  for (int k0 = 0; k0 < K; k0 += 32) {
    __syncthreads();                      // previous iter's readers done
    gload16(Ag0 + k0,          AsB);
    gload16(Ag0 + k0 + 16 * K, AsB + 1024);
    gload16(Bg0 + k0,          BsB);
    gload16(Bg0 + k0 + 16 * K, BsB + 1024);
    __syncthreads();                      // drains vmcnt(0): tiles ready
    bf16x8 a[4], b[4];
    #pragma unroll
    for (int m = 0; m < 4; ++m) a[m] = *(const bf16x8*)(Ar + m * 512);
    #pragma unroll
    for (int n = 0; n < 4; ++n) b[n] = *(const bf16x8*)(Br + n * 512);
    #pragma unroll
    for (int m = 0; m < 4; ++m)
      #pragma unroll
      for (int n = 0; n < 4; ++n)
        acc[m][n] = __builtin_amdgcn_mfma_f32_16x16x32_bf16(a[m], b[n], acc[m][n], 0, 0, 0);
  }

  // C/D layout: col = lane&15, row = (lane>>4)*4 + reg   [m89/m91 verified]
  const int rq4 = (lane >> 4) * 4;
  if (MODE == 0) {
    const int which = n0 >> 12;          // 0=q 1=k 2=v
    const int h     = (n0 >> 7) & 31;
    ushort* dst0 = (ushort*)outp + (size_t)which * TEN + (size_t)h * (SEQ * HD);
    #pragma unroll
    for (int n = 0; n < 4; ++n) {
      const int d = wc * 64 + n * 16 + fl;
      const float bv = bias[n0 + d];
      #pragma unroll
      for (int m = 0; m < 4; ++m) {
        const int rowb = m0 + wr * 64 + m * 16 + rq4;
        #pragma unroll
        for (int r = 0; r < 4; ++r) {
          const int t = rowb + r;
          const int b = t >> 11, s = t & 2047;
          dst0[(size_t)b * (NH * SEQ * HD) + (size_t)s * HD + d] = f2bf(acc[m][n][r] + bv);
        }
      }
    }
  } else {
    float* C = (float*)outp;
    #pragma unroll
    for (int n = 0; n < 4; ++n) {
      const int d = wc * 64 + n * 16 + fl;
      #pragma unroll
      for (int m = 0; m < 4; ++m) {
        const int rowb = m0 + wr * 64 + m * 16 + rq4;
        #pragma unroll
        for (int r = 0; r < 4; ++r)
          C[(size_t)(rowb + r) * N + n0 + d] = acc[m][n][r];
      }
    }
  }
}

// ---------------------------------------------------------------------------
// NeoX RoPE on bf16 q,k in place; one thread handles (bh,s,d) for BOTH q,k.
// Q folded with SCALE. exp2f replaces powf; sincosf keeps fp32 range reduction.
// ---------------------------------------------------------------------------
__global__ __launch_bounds__(256) void rope_kernel(ushort* __restrict__ qbuf,
                                                   ushort* __restrict__ kbuf,
                                                   const int* __restrict__ positions) {
  const int idx = blockIdx.x * 256 + threadIdx.x;
  const int d  = idx & 63;
  const int s  = (idx >> 6) & 2047;
  const int bh = idx >> 17;            // 0..63
  const size_t off = ((size_t)bh * SEQ + s) * HD;
  const int pos = positions[(bh >> 5) * SEQ + s];
  const float invf = exp2f(-(float)d * 0.20762050593046014f);  // log2(1e4)/64
  const float ang = (float)pos * invf;
  float sn, cs;
  sincosf(ang, &sn, &cs);
  {
    float x1 = bfl(qbuf[off + d]), x2 = bfl(qbuf[off + d + 64]);
    qbuf[off + d]      = f2bf((x1 * cs - x2 * sn) * SCALE);
    qbuf[off + d + 64] = f2bf((x2 * cs + x1 * sn) * SCALE);
  }
  {
    float x1 = bfl(kbuf[off + d]), x2 = bfl(kbuf[off + d + 64]);
    kbuf[off + d]      = f2bf(x1 * cs - x2 * sn);
    kbuf[off + d + 64] = f2bf(x2 * cs + x1 * sn);
  }
}

// ---------------------------------------------------------------------------
// fp32 causal flash attention; bf16 Q/K/V in (unpacked to fp32 at LDS stage),
// bf16 out (feeds proj GEMM). Structure identical to round-1 (passed).
// ---------------------------------------------------------------------------
__global__ __launch_bounds__(256) void attn_kernel(const ushort* __restrict__ Q,
                                                   const ushort* __restrict__ K,
                                                   const ushort* __restrict__ V,
                                                   ushort* __restrict__ Out) {
  constexpr int QBLK = 16, KVBLK = 64, KP = 132;
  __shared__ float q_lds[QBLK][KP];
  __shared__ float k_lds[KVBLK][KP];
  __shared__ float v_lds[KVBLK][KP];
  __shared__ float p_lds[QBLK][KVBLK];
  const int tid = threadIdx.x;
  const int r = tid >> 4, g = tid & 15;
  const int qs = blockIdx.x * QBLK;
  const int bh = blockIdx.y;
  const ushort* Qb = Q + (size_t)bh * SEQ * HD;
  const ushort* Kb = K + (size_t)bh * SEQ * HD;
  const ushort* Vb = V + (size_t)bh * SEQ * HD;

  {
    const int rr = tid >> 4, d0 = (tid & 15) * 8;
    uint4 raw = *(const uint4*)(Qb + (size_t)(qs + rr) * HD + d0);
    UNPK8(raw, &q_lds[rr][d0]);
  }

  float m = -INFINITY, lsum = 0.f;
  float o[8] = {0, 0, 0, 0, 0, 0, 0, 0};
  const int qrow = qs + r;
  const int nt = (qs + QBLK + KVBLK - 1) / KVBLK;

  for (int jt = 0; jt < nt; ++jt) {
    const int j0 = jt * KVBLK;
    __syncthreads();
    #pragma unroll
    for (int l = 0; l < 4; ++l) {
      const int idx = tid + l * 256;
      const int rr = idx >> 4, d0 = (idx & 15) * 8;
      uint4 rk = *(const uint4*)(Kb + (size_t)(j0 + rr) * HD + d0);
      UNPK8(rk, &k_lds[rr][d0]);
      uint4 rv = *(const uint4*)(Vb + (size_t)(j0 + rr) * HD + d0);
      UNPK8(rv, &v_lds[rr][d0]);
    }
    __syncthreads();

    float sc[4] = {0, 0, 0, 0};
    for (int dq = 0; dq < 32; ++dq) {
      float4 qv = *(const float4*)(&q_lds[r][4 * dq]);
      #pragma unroll
      for (int cc = 0; cc < 4; ++cc) {
        const int c = g + 16 * cc;
        float4 kv = *(const float4*)(&k_lds[c][4 * dq]);
        sc[cc] = fmaf(qv.x, kv.x, sc[cc]);
        sc[cc] = fmaf(qv.y, kv.y, sc[cc]);
        sc[cc] = fmaf(qv.z, kv.z, sc[cc]);
        sc[cc] = fmaf(qv.w, kv.w, sc[cc]);
      }
    }

    float tmax = -INFINITY;
    #pragma unroll
    for (int cc = 0; cc < 4; ++cc) {
      if (j0 + g + 16 * cc > qrow) sc[cc] = -INFINITY;  // causal mask
      tmax = fmaxf(tmax, sc[cc]);
    }
    #pragma unroll
    for (int off = 1; off < 16; off <<= 1)
      tmax = fmaxf(tmax, __shfl_xor(tmax, off));
    const float mnew = fmaxf(m, tmax);
    const float rescale = __expf(m - mnew);
    float psum = 0.f;
    #pragma unroll
    for (int cc = 0; cc < 4; ++cc) {
      float p = __expf(sc[cc] - mnew);
      p_lds[r][g + 16 * cc] = p;          // same 16-lane group of same wave
      psum += p;
    }
    #pragma unroll
    for (int off = 1; off < 16; off <<= 1)
      psum += __shfl_xor(psum, off);
    lsum = lsum * rescale + psum;
    m = mnew;
    #pragma unroll
    for (int k = 0; k < 8; ++k) o[k] *= rescale;

    for (int c = 0; c < KVBLK; ++c) {
      const float p = p_lds[r][c];
      float4 va  = *(const float4*)(&v_lds[c][8 * g]);
      float4 vb4 = *(const float4*)(&v_lds[c][8 * g + 4]);
      o[0] = fmaf(p, va.x,  o[0]); o[1] = fmaf(p, va.y,  o[1]);
      o[2] = fmaf(p, va.z,  o[2]); o[3] = fmaf(p, va.w,  o[3]);
      o[4] = fmaf(p, vb4.x, o[4]); o[5] = fmaf(p, vb4.y, o[5]);
      o[6] = fmaf(p, vb4.z, o[6]); o[7] = fmaf(p, vb4.w, o[7]);
    }
  }

  const float inv = 1.0f / lsum;
  const int b = bh >> 5, h = bh & 31;
  ushort* dst = Out + ((size_t)(b * SEQ + qrow)) * HID + h * HD + 8 * g;
  uint4 pk;
  pk.x = (uint)f2bf(o[0] * inv) | ((uint)f2bf(o[1] * inv) << 16);
  pk.y = (uint)f2bf(o[2] * inv) | ((uint)f2bf(o[3] * inv) << 16);
  pk.z = (uint)f2bf(o[4] * inv) | ((uint)f2bf(o[5] * inv) << 16);
  pk.w = (uint)f2bf(o[6] * inv) | ((uint)f2bf(o[7] * inv) << 16);
  *(uint4*)dst = pk;
}

// ---------------------------------------------------------------------------
extern "C" void kernel_launch(void* const* d_in, const int* in_sizes, int n_in,
                              void* d_out, int out_size, void* d_ws, size_t ws_size,
                              hipStream_t stream) {
  const int*   positions = (const int*)d_in[0];
  const float* hidden    = (const float*)d_in[1];
  const float* w_qkv     = (const float*)d_in[2];
  const float* b_qkv     = (const float*)d_in[3];
  const float* w_proj    = (const float*)d_in[4];
  float* out = (float*)d_out;

  // ws (bf16 elements): q | k | v | wT(12288x4096, reused for wprojT) | hA(=attn out)
  ushort* ws16 = (ushort*)d_ws;
  ushort* qb = ws16;
  ushort* kb = ws16 + TEN;
  ushort* vb = ws16 + 2 * TEN;
  ushort* wT = ws16 + 3 * TEN;
  ushort* hA = ws16 + 3 * TEN + (size_t)(3 * HID) * HID;  // total ~235 MB

  conv_bf16<<<8192, 256, 0, stream>>>(hidden, hA);
  transp_bf16<<<dim3(3 * HID / 32, HID / 32), 256, 0, stream>>>(w_qkv, wT, HID, 3 * HID);
  gemm_mfma<0><<<dim3(3 * HID / 128, 32), 256, 0, stream>>>(hA, wT, b_qkv, (void*)qb,
                                                            3 * HID, HID);
  rope_kernel<<<32768, 256, 0, stream>>>(qb, kb, positions);
  transp_bf16<<<dim3(HID / 32, HID / 32), 256, 0, stream>>>(w_proj, wT, HID, HID);
  attn_kernel<<<dim3(SEQ / 16, B_ * NH), 256, 0, stream>>>(qb, kb, vb, hA);
  gemm_mfma<1><<<dim3(HID / 128, 32), 256, 0, stream>>>(hA, wT, nullptr, (void*)out,
                                                        HID, HID);
}

// Round 6
// 1959.640 us; speedup vs baseline: 5.5792x; 2.7148x over previous
//
#include <hip/hip_runtime.h>
#include <hip/hip_bf16.h>
#include <math.h>

constexpr int B_   = 2;
constexpr int SEQ  = 2048;
constexpr int HID  = 4096;
constexpr int NH   = 32;
constexpr int HD   = 128;
constexpr float SCALE = 0.08838834764831845f;  // 128^-0.5
constexpr size_t TEN = (size_t)B_ * NH * SEQ * HD;  // 16,777,216 per tensor

typedef __attribute__((ext_vector_type(8))) __bf16 bf16x8;
typedef __attribute__((ext_vector_type(4))) float f32x4;

__device__ __forceinline__ ushort f2bf(float f) {  // RNE fp32->bf16
  uint u = __float_as_uint(f);
  return (ushort)((u + 0x7fffu + ((u >> 16) & 1u)) >> 16);
}
__device__ __forceinline__ float bfl(uint u) { return __uint_as_float(u << 16); }

__device__ __forceinline__ void gload16(const void* g, void* l) {
  __builtin_amdgcn_global_load_lds((__attribute__((address_space(1))) void*)(g),
                                   (__attribute__((address_space(3))) void*)(l),
                                   16, 0, 0);
}

// ---------------------------------------------------------------------------
// fp32 -> bf16 straight convert (n divisible by 2048)
// ---------------------------------------------------------------------------
__global__ __launch_bounds__(256) void conv_bf16(const float* __restrict__ in,
                                                 ushort* __restrict__ out) {
  const size_t i = ((size_t)blockIdx.x * 256 + threadIdx.x) * 8;
  float4 x = *(const float4*)(in + i);
  float4 y = *(const float4*)(in + i + 4);
  uint4 pk;
  pk.x = (uint)f2bf(x.x) | ((uint)f2bf(x.y) << 16);
  pk.y = (uint)f2bf(x.z) | ((uint)f2bf(x.w) << 16);
  pk.z = (uint)f2bf(y.x) | ((uint)f2bf(y.y) << 16);
  pk.w = (uint)f2bf(y.z) | ((uint)f2bf(y.w) << 16);
  *(uint4*)(out + i) = pk;
}

// ---------------------------------------------------------------------------
// transpose + convert: in [R][C] fp32 -> out [C][R] bf16  (R,C mult of 32)
// ---------------------------------------------------------------------------
__global__ __launch_bounds__(256) void transp_bf16(const float* __restrict__ in,
                                                   ushort* __restrict__ out,
                                                   int R, int C) {
  __shared__ float t[32][33];
  const int tx = threadIdx.x & 31, ty = threadIdx.x >> 5;
  const int c0 = blockIdx.x * 32, r0 = blockIdx.y * 32;
  #pragma unroll
  for (int i = 0; i < 4; ++i)
    t[ty + 8*i][tx] = in[(size_t)(r0 + ty + 8*i) * C + c0 + tx];
  __syncthreads();
  #pragma unroll
  for (int i = 0; i < 4; ++i)
    out[(size_t)(c0 + ty + 8*i) * R + r0 + tx] = f2bf(t[tx][ty + 8*i]);
}

// ---------------------------------------------------------------------------
// bf16 MFMA GEMM, m97 structure: C = A(MxK) @ Bt(NxK)^T.  128x128 tile, BK=32,
// 4 waves (2x2), 4x4 frags of 16x16x32 per wave, global_load_lds width=16.
// MODE 0: +bias, scatter bf16 into q/k/v [B*NH][SEQ][HD] (outp = q base)
// MODE 1: plain fp32 row-major store
// ---------------------------------------------------------------------------
template<int MODE>
__global__ __launch_bounds__(256) void gemm_mfma(const ushort* __restrict__ A,
                                                 const ushort* __restrict__ Bt,
                                                 const float* __restrict__ bias,
                                                 void* __restrict__ outp,
                                                 int N, int K) {
  __shared__ __align__(16) ushort As[128 * 32];
  __shared__ __align__(16) ushort Bs[128 * 32];
  const int tid = threadIdx.x;
  const int wave = tid >> 6, lane = tid & 63;
  const int wr = wave >> 1, wc = wave & 1;
  const int m0 = blockIdx.y * 128, n0 = blockIdx.x * 128;

  f32x4 acc[4][4];
  #pragma unroll
  for (int i = 0; i < 4; ++i)
    #pragma unroll
    for (int j = 0; j < 4; ++j) acc[i][j] = (f32x4){0.f, 0.f, 0.f, 0.f};

  const int srow = 32 * wave + (lane >> 2);
  const int skq8 = (lane & 3) * 8;
  const ushort* Ag0 = A  + (size_t)(m0 + srow) * K + skq8;
  const ushort* Bg0 = Bt + (size_t)(n0 + srow) * K + skq8;
  char* AsB = (char*)As + wave * 2048;
  char* BsB = (char*)Bs + wave * 2048;

  const int fl  = lane & 15;
  const int kh8 = (lane >> 4) * 8;
  const ushort* Ar = As + (wr * 64 + fl) * 32 + kh8;
  const ushort* Br = Bs + (wc * 64 + fl) * 32 + kh8;

  for (int k0 = 0; k0 < K; k0 += 32) {
    __syncthreads();
    gload16(Ag0 + k0,          AsB);
    gload16(Ag0 + k0 + 16 * K, AsB + 1024);
    gload16(Bg0 + k0,          BsB);
    gload16(Bg0 + k0 + 16 * K, BsB + 1024);
    __syncthreads();
    bf16x8 a[4], b[4];
    #pragma unroll
    for (int m = 0; m < 4; ++m) a[m] = *(const bf16x8*)(Ar + m * 512);
    #pragma unroll
    for (int n = 0; n < 4; ++n) b[n] = *(const bf16x8*)(Br + n * 512);
    #pragma unroll
    for (int m = 0; m < 4; ++m)
      #pragma unroll
      for (int n = 0; n < 4; ++n)
        acc[m][n] = __builtin_amdgcn_mfma_f32_16x16x32_bf16(a[m], b[n], acc[m][n], 0, 0, 0);
  }

  const int rq4 = (lane >> 4) * 4;
  if (MODE == 0) {
    const int which = n0 >> 12;
    const int h     = (n0 >> 7) & 31;
    ushort* dst0 = (ushort*)outp + (size_t)which * TEN + (size_t)h * (SEQ * HD);
    #pragma unroll
    for (int n = 0; n < 4; ++n) {
      const int d = wc * 64 + n * 16 + fl;
      const float bv = bias[n0 + d];
      #pragma unroll
      for (int m = 0; m < 4; ++m) {
        const int rowb = m0 + wr * 64 + m * 16 + rq4;
        #pragma unroll
        for (int r = 0; r < 4; ++r) {
          const int t = rowb + r;
          const int b = t >> 11, s = t & 2047;
          dst0[(size_t)b * (NH * SEQ * HD) + (size_t)s * HD + d] = f2bf(acc[m][n][r] + bv);
        }
      }
    }
  } else {
    float* C = (float*)outp;
    #pragma unroll
    for (int n = 0; n < 4; ++n) {
      const int d = wc * 64 + n * 16 + fl;
      #pragma unroll
      for (int m = 0; m < 4; ++m) {
        const int rowb = m0 + wr * 64 + m * 16 + rq4;
        #pragma unroll
        for (int r = 0; r < 4; ++r)
          C[(size_t)(rowb + r) * N + n0 + d] = acc[m][n][r];
      }
    }
  }
}

// ---------------------------------------------------------------------------
// NeoX RoPE on bf16 q,k in place; SCALE folded into q.
// ---------------------------------------------------------------------------
__global__ __launch_bounds__(256) void rope_kernel(ushort* __restrict__ qbuf,
                                                   ushort* __restrict__ kbuf,
                                                   const int* __restrict__ positions) {
  const int idx = blockIdx.x * 256 + threadIdx.x;
  const int d  = idx & 63;
  const int s  = (idx >> 6) & 2047;
  const int bh = idx >> 17;            // 0..63
  const size_t off = ((size_t)bh * SEQ + s) * HD;
  const int pos = positions[(bh >> 5) * SEQ + s];
  const float invf = exp2f(-(float)d * 0.20762050593046014f);  // log2(1e4)/64
  const float ang = (float)pos * invf;
  float sn, cs;
  sincosf(ang, &sn, &cs);
  {
    float x1 = bfl(qbuf[off + d]), x2 = bfl(qbuf[off + d + 64]);
    qbuf[off + d]      = f2bf((x1 * cs - x2 * sn) * SCALE);
    qbuf[off + d + 64] = f2bf((x2 * cs + x1 * sn) * SCALE);
  }
  {
    float x1 = bfl(kbuf[off + d]), x2 = bfl(kbuf[off + d + 64]);
    kbuf[off + d]      = f2bf(x1 * cs - x2 * sn);
    kbuf[off + d + 64] = f2bf(x2 * cs + x1 * sn);
  }
}

// ---------------------------------------------------------------------------
// bf16 MFMA causal flash attention.
// Grid (SEQ/64, B*NH), 256 thr (4 waves x 16 q-rows). KVBLK=64.
// Q in registers. K staged via global_load_lds with pre-swizzled source
// (block ^= row&7).  V staged transposed to Vt[d][kv] (pair-packed b32
// writes), swizzled with block ^= (d>>3)&7.  P in per-wave LDS, block ^= q&7.
// Frag conventions identical to gemm_mfma (validated r3).
// ---------------------------------------------------------------------------
__global__ __launch_bounds__(256) void attn_mfma(const ushort* __restrict__ Q,
                                                 const ushort* __restrict__ K,
                                                 const ushort* __restrict__ V,
                                                 ushort* __restrict__ Out) {
  __shared__ __align__(16) ushort Ks[64 * 128];    // 16 KB, [kv][k] swizzled
  __shared__ __align__(16) ushort Vt[128 * 64];    // 16 KB, [d][kv] swizzled
  __shared__ __align__(16) ushort Pl[4 * 16 * 64]; // 8 KB, per-wave [q][kv] swizzled
  const int tid  = threadIdx.x;
  const int wave = tid >> 6, lane = tid & 63;
  const int fl = lane & 15, hh = lane >> 4;        // frag row / k-group
  const int qs   = blockIdx.x * 64;
  const int qs_w = qs + wave * 16;
  const int bh   = blockIdx.y;
  const ushort* Qb = Q + (size_t)bh * SEQ * HD;
  const ushort* Kb = K + (size_t)bh * SEQ * HD;
  const ushort* Vb = V + (size_t)bh * SEQ * HD;

  // ---- Q fragments in registers: A[row=fl][k=hh*8+j+32kk]
  bf16x8 qa[4];
  {
    const ushort* qrow = Qb + (size_t)(qs_w + fl) * HD + hh * 8;
    #pragma unroll
    for (int kk = 0; kk < 4; ++kk)
      qa[kk] = *(const bf16x8*)(qrow + 32 * kk);
  }

  f32x4 o_acc[8];
  #pragma unroll
  for (int dt = 0; dt < 8; ++dt) o_acc[dt] = (f32x4){0.f, 0.f, 0.f, 0.f};
  float mrow[4] = {-INFINITY, -INFINITY, -INFINITY, -INFINITY};
  float lrow[4] = {0.f, 0.f, 0.f, 0.f};

  char* KsC = (char*)Ks;
  char* VtC = (char*)Vt;
  ushort* Pw = Pl + wave * (16 * 64);

  const int nt = qs / 64 + 1;
  for (int jt = 0; jt < nt; ++jt) {
    const int j0 = jt * 64;
    __syncthreads();                       // prev-iter LDS readers done

    // ---- stage K: 16 segments of 1 KB (4 rows each); pre-swizzled source
    #pragma unroll
    for (int i = 0; i < 4; ++i) {
      const int seg = i * 4 + wave;
      const int row = 4 * seg + hh;        // uses lane>>4 of dest mapping
      const int gc  = fl ^ (row & 7);      // 16B-block pre-swizzle
      gload16(Kb + (size_t)(j0 + row) * HD + gc * 8, KsC + seg * 1024);
    }
    // ---- stage V transposed: thread handles 2 (pair, dchunk) units
    #pragma unroll
    for (int a = 0; a < 2; ++a) {
      const int idx   = tid + a * 256;     // 0..511
      const int chunk = idx & 15;          // d-chunk (8 d's)
      const int pair  = idx >> 4;          // kv pair (2 rows)
      const int d0    = chunk * 8;
      uint4 v0 = *(const uint4*)(Vb + (size_t)(j0 + 2 * pair) * HD + d0);
      uint4 v1 = *(const uint4*)(Vb + (size_t)(j0 + 2 * pair + 1) * HD + d0);
      const ushort* u0 = (const ushort*)&v0;
      const ushort* u1 = (const ushort*)&v1;
      #pragma unroll
      for (int j = 0; j < 8; ++j) {
        const int d = d0 + j;
        const int byt = (d * 128 + pair * 4) ^ (((d >> 3) & 7) << 4);
        *(uint*)(VtC + byt) = (uint)u0[j] | ((uint)u1[j] << 16);
      }
    }
    __syncthreads();                       // drains vmcnt + lgkm: tiles ready

    // ---- QK^T: S[16q x 64kv] per wave
    f32x4 sa[4];
    #pragma unroll
    for (int cc = 0; cc < 4; ++cc) sa[cc] = (f32x4){0.f, 0.f, 0.f, 0.f};
    #pragma unroll
    for (int cc = 0; cc < 4; ++cc) {
      const int row = fl + 16 * cc;        // kv row within tile
      const int rsw = row & 7;
      #pragma unroll
      for (int kk = 0; kk < 4; ++kk) {
        bf16x8 kb = *(const bf16x8*)(KsC + row * 256 + ((hh + 4 * kk) ^ rsw) * 16);
        sa[cc] = __builtin_amdgcn_mfma_f32_16x16x32_bf16(qa[kk], kb, sa[cc], 0, 0, 0);
      }
    }

    // ---- causal mask (diagonal tile only)
    if (jt == nt - 1) {
      #pragma unroll
      for (int cc = 0; cc < 4; ++cc) {
        const int kv_g = j0 + fl + 16 * cc;
        #pragma unroll
        for (int r = 0; r < 4; ++r)
          if (kv_g > qs_w + 4 * hh + r) sa[cc][r] = -3.0e38f;
      }
    }

    // ---- online softmax (per q-row r; row lives across the 16-lane fl group)
    float tmax[4], psum[4], resc[4];
    #pragma unroll
    for (int r = 0; r < 4; ++r) {
      float t = fmaxf(fmaxf(sa[0][r], sa[1][r]), fmaxf(sa[2][r], sa[3][r]));
      #pragma unroll
      for (int off = 1; off < 16; off <<= 1)
        t = fmaxf(t, __shfl_xor(t, off));
      tmax[r] = t;
    }
    #pragma unroll
    for (int r = 0; r < 4; ++r) {
      const float mnew = fmaxf(mrow[r], tmax[r]);
      resc[r] = __expf(mrow[r] - mnew);
      mrow[r] = mnew;
      float ps = 0.f;
      #pragma unroll
      for (int cc = 0; cc < 4; ++cc) {
        const float p = __expf(sa[cc][r] - mnew);
        sa[cc][r] = p;
        ps += p;
      }
      psum[r] = ps;
    }
    #pragma unroll
    for (int r = 0; r < 4; ++r) {
      float ps = psum[r];
      #pragma unroll
      for (int off = 1; off < 16; off <<= 1)
        ps += __shfl_xor(ps, off);
      lrow[r] = lrow[r] * resc[r] + ps;
    }
    #pragma unroll
    for (int dt = 0; dt < 8; ++dt)
      #pragma unroll
      for (int r = 0; r < 4; ++r) o_acc[dt][r] *= resc[r];

    // ---- P -> bf16 -> per-wave LDS (swizzled: block ^= q&7)
    #pragma unroll
    for (int cc = 0; cc < 4; ++cc) {
      const int kv = fl + 16 * cc;
      #pragma unroll
      for (int r = 0; r < 4; ++r) {
        const int q = 4 * hh + r;
        const int byt = q * 128 + (((kv >> 3) ^ (q & 7)) << 4) + (kv & 7) * 2;
        *(ushort*)((char*)Pw + byt) = f2bf(sa[cc][r]);
      }
    }

    // ---- PV: O[16q x 128d] += P[16 x 64] * V[64 x 128]
    #pragma unroll
    for (int chunk = 0; chunk < 2; ++chunk) {
      bf16x8 pa = *(const bf16x8*)((char*)Pw + fl * 128 +
                                   (((hh + 4 * chunk) ^ (fl & 7)) << 4));
      #pragma unroll
      for (int dt = 0; dt < 8; ++dt) {
        const int d = fl + 16 * dt;
        bf16x8 vbf = *(const bf16x8*)(VtC + ((d * 128 + hh * 16 + 64 * chunk) ^
                                             (((d >> 3) & 7) << 4)));
        o_acc[dt] = __builtin_amdgcn_mfma_f32_16x16x32_bf16(pa, vbf, o_acc[dt], 0, 0, 0);
      }
    }
  }

  // ---- epilogue: normalize rows, write bf16 to Out [B*SEQ][HID]
  float inv[4];
  #pragma unroll
  for (int r = 0; r < 4; ++r) inv[r] = 1.0f / lrow[r];
  const int b = bh >> 5, h = bh & 31;
  #pragma unroll
  for (int dt = 0; dt < 8; ++dt) {
    const int d = h * HD + dt * 16 + fl;
    #pragma unroll
    for (int r = 0; r < 4; ++r) {
      const int row_g = qs_w + 4 * hh + r;
      Out[((size_t)(b * SEQ + row_g)) * HID + d] = f2bf(o_acc[dt][r] * inv[r]);
    }
  }
}

// ---------------------------------------------------------------------------
extern "C" void kernel_launch(void* const* d_in, const int* in_sizes, int n_in,
                              void* d_out, int out_size, void* d_ws, size_t ws_size,
                              hipStream_t stream) {
  const int*   positions = (const int*)d_in[0];
  const float* hidden    = (const float*)d_in[1];
  const float* w_qkv     = (const float*)d_in[2];
  const float* b_qkv     = (const float*)d_in[3];
  const float* w_proj    = (const float*)d_in[4];
  float* out = (float*)d_out;

  ushort* ws16 = (ushort*)d_ws;
  ushort* qb = ws16;
  ushort* kb = ws16 + TEN;
  ushort* vb = ws16 + 2 * TEN;
  ushort* wT = ws16 + 3 * TEN;
  ushort* hA = ws16 + 3 * TEN + (size_t)(3 * HID) * HID;

  conv_bf16<<<8192, 256, 0, stream>>>(hidden, hA);
  transp_bf16<<<dim3(3 * HID / 32, HID / 32), 256, 0, stream>>>(w_qkv, wT, HID, 3 * HID);
  gemm_mfma<0><<<dim3(3 * HID / 128, 32), 256, 0, stream>>>(hA, wT, b_qkv, (void*)qb,
                                                            3 * HID, HID);
  rope_kernel<<<32768, 256, 0, stream>>>(qb, kb, positions);
  transp_bf16<<<dim3(HID / 32, HID / 32), 256, 0, stream>>>(w_proj, wT, HID, HID);
  attn_mfma<<<dim3(SEQ / 64, B_ * NH), 256, 0, stream>>>(qb, kb, vb, hA);
  gemm_mfma<1><<<dim3(HID / 128, 32), 256, 0, stream>>>(hA, wT, nullptr, (void*)out,
                                                        HID, HID);
}

// Round 7
// 1600.107 us; speedup vs baseline: 6.8328x; 1.2247x over previous
//
#include <hip/hip_runtime.h>
#include <hip/hip_bf16.h>
#include <math.h>

constexpr int B_   = 2;
constexpr int SEQ  = 2048;
constexpr int HID  = 4096;
constexpr int NH   = 32;
constexpr int HD   = 128;
constexpr float SCALE = 0.08838834764831845f;  // 128^-0.5
constexpr size_t TEN = (size_t)B_ * NH * SEQ * HD;  // 16,777,216 per tensor

typedef __attribute__((ext_vector_type(8))) __bf16 bf16x8;
typedef __attribute__((ext_vector_type(4))) float f32x4;

__device__ __forceinline__ ushort f2bf(float f) {  // RNE fp32->bf16
  uint u = __float_as_uint(f);
  return (ushort)((u + 0x7fffu + ((u >> 16) & 1u)) >> 16);
}
__device__ __forceinline__ float bfl(uint u) { return __uint_as_float(u << 16); }

__device__ __forceinline__ void gload16(const void* g, void* l) {
  __builtin_amdgcn_global_load_lds((__attribute__((address_space(1))) void*)(g),
                                   (__attribute__((address_space(3))) void*)(l),
                                   16, 0, 0);
}

// ---------------------------------------------------------------------------
// fp32 -> bf16 straight convert (n divisible by 2048)
// ---------------------------------------------------------------------------
__global__ __launch_bounds__(256) void conv_bf16(const float* __restrict__ in,
                                                 ushort* __restrict__ out) {
  const size_t i = ((size_t)blockIdx.x * 256 + threadIdx.x) * 8;
  float4 x = *(const float4*)(in + i);
  float4 y = *(const float4*)(in + i + 4);
  uint4 pk;
  pk.x = (uint)f2bf(x.x) | ((uint)f2bf(x.y) << 16);
  pk.y = (uint)f2bf(x.z) | ((uint)f2bf(x.w) << 16);
  pk.z = (uint)f2bf(y.x) | ((uint)f2bf(y.y) << 16);
  pk.w = (uint)f2bf(y.z) | ((uint)f2bf(y.w) << 16);
  *(uint4*)(out + i) = pk;
}

// ---------------------------------------------------------------------------
// transpose + convert: in [R][C] fp32 -> out [C][R] bf16  (R,C mult of 32)
// ---------------------------------------------------------------------------
__global__ __launch_bounds__(256) void transp_bf16(const float* __restrict__ in,
                                                   ushort* __restrict__ out,
                                                   int R, int C) {
  __shared__ float t[32][33];
  const int tx = threadIdx.x & 31, ty = threadIdx.x >> 5;
  const int c0 = blockIdx.x * 32, r0 = blockIdx.y * 32;
  #pragma unroll
  for (int i = 0; i < 4; ++i)
    t[ty + 8*i][tx] = in[(size_t)(r0 + ty + 8*i) * C + c0 + tx];
  __syncthreads();
  #pragma unroll
  for (int i = 0; i < 4; ++i)
    out[(size_t)(c0 + ty + 8*i) * R + r0 + tx] = f2bf(t[tx][ty + 8*i]);
}

// ---------------------------------------------------------------------------
// bf16 MFMA GEMM, m97 structure: C = A(MxK) @ Bt(NxK)^T.  128x128 tile, BK=32,
// 4 waves (2x2), 4x4 frags of 16x16x32 per wave, global_load_lds width=16.
// MODE 0: +bias, scatter bf16 into q/k/v [B*NH][SEQ][HD] (outp = q base)
// MODE 1: plain fp32 row-major store
// ---------------------------------------------------------------------------
template<int MODE>
__global__ __launch_bounds__(256) void gemm_mfma(const ushort* __restrict__ A,
                                                 const ushort* __restrict__ Bt,
                                                 const float* __restrict__ bias,
                                                 void* __restrict__ outp,
                                                 int N, int K) {
  __shared__ __align__(16) ushort As[128 * 32];
  __shared__ __align__(16) ushort Bs[128 * 32];
  const int tid = threadIdx.x;
  const int wave = tid >> 6, lane = tid & 63;
  const int wr = wave >> 1, wc = wave & 1;
  const int m0 = blockIdx.y * 128, n0 = blockIdx.x * 128;

  f32x4 acc[4][4];
  #pragma unroll
  for (int i = 0; i < 4; ++i)
    #pragma unroll
    for (int j = 0; j < 4; ++j) acc[i][j] = (f32x4){0.f, 0.f, 0.f, 0.f};

  const int srow = 32 * wave + (lane >> 2);
  const int skq8 = (lane & 3) * 8;
  const ushort* Ag0 = A  + (size_t)(m0 + srow) * K + skq8;
  const ushort* Bg0 = Bt + (size_t)(n0 + srow) * K + skq8;
  char* AsB = (char*)As + wave * 2048;
  char* BsB = (char*)Bs + wave * 2048;

  const int fl  = lane & 15;
  const int kh8 = (lane >> 4) * 8;
  const ushort* Ar = As + (wr * 64 + fl) * 32 + kh8;
  const ushort* Br = Bs + (wc * 64 + fl) * 32 + kh8;

  for (int k0 = 0; k0 < K; k0 += 32) {
    __syncthreads();
    gload16(Ag0 + k0,          AsB);
    gload16(Ag0 + k0 + 16 * K, AsB + 1024);
    gload16(Bg0 + k0,          BsB);
    gload16(Bg0 + k0 + 16 * K, BsB + 1024);
    __syncthreads();
    bf16x8 a[4], b[4];
    #pragma unroll
    for (int m = 0; m < 4; ++m) a[m] = *(const bf16x8*)(Ar + m * 512);
    #pragma unroll
    for (int n = 0; n < 4; ++n) b[n] = *(const bf16x8*)(Br + n * 512);
    #pragma unroll
    for (int m = 0; m < 4; ++m)
      #pragma unroll
      for (int n = 0; n < 4; ++n)
        acc[m][n] = __builtin_amdgcn_mfma_f32_16x16x32_bf16(a[m], b[n], acc[m][n], 0, 0, 0);
  }

  const int rq4 = (lane >> 4) * 4;
  if (MODE == 0) {
    const int which = n0 >> 12;
    const int h     = (n0 >> 7) & 31;
    ushort* dst0 = (ushort*)outp + (size_t)which * TEN + (size_t)h * (SEQ * HD);
    #pragma unroll
    for (int n = 0; n < 4; ++n) {
      const int d = wc * 64 + n * 16 + fl;
      const float bv = bias[n0 + d];
      #pragma unroll
      for (int m = 0; m < 4; ++m) {
        const int rowb = m0 + wr * 64 + m * 16 + rq4;
        #pragma unroll
        for (int r = 0; r < 4; ++r) {
          const int t = rowb + r;
          const int b = t >> 11, s = t & 2047;
          dst0[(size_t)b * (NH * SEQ * HD) + (size_t)s * HD + d] = f2bf(acc[m][n][r] + bv);
        }
      }
    }
  } else {
    float* C = (float*)outp;
    #pragma unroll
    for (int n = 0; n < 4; ++n) {
      const int d = wc * 64 + n * 16 + fl;
      #pragma unroll
      for (int m = 0; m < 4; ++m) {
        const int rowb = m0 + wr * 64 + m * 16 + rq4;
        #pragma unroll
        for (int r = 0; r < 4; ++r)
          C[(size_t)(rowb + r) * N + n0 + d] = acc[m][n][r];
      }
    }
  }
}

// ---------------------------------------------------------------------------
// NeoX RoPE on bf16 q,k in place; SCALE folded into q.
// ---------------------------------------------------------------------------
__global__ __launch_bounds__(256) void rope_kernel(ushort* __restrict__ qbuf,
                                                   ushort* __restrict__ kbuf,
                                                   const int* __restrict__ positions) {
  const int idx = blockIdx.x * 256 + threadIdx.x;
  const int d  = idx & 63;
  const int s  = (idx >> 6) & 2047;
  const int bh = idx >> 17;            // 0..63
  const size_t off = ((size_t)bh * SEQ + s) * HD;
  const int pos = positions[(bh >> 5) * SEQ + s];
  const float invf = exp2f(-(float)d * 0.20762050593046014f);  // log2(1e4)/64
  const float ang = (float)pos * invf;
  float sn, cs;
  sincosf(ang, &sn, &cs);
  {
    float x1 = bfl(qbuf[off + d]), x2 = bfl(qbuf[off + d + 64]);
    qbuf[off + d]      = f2bf((x1 * cs - x2 * sn) * SCALE);
    qbuf[off + d + 64] = f2bf((x2 * cs + x1 * sn) * SCALE);
  }
  {
    float x1 = bfl(kbuf[off + d]), x2 = bfl(kbuf[off + d + 64]);
    kbuf[off + d]      = f2bf(x1 * cs - x2 * sn);
    kbuf[off + d + 64] = f2bf(x2 * cs + x1 * sn);
  }
}

// ---------------------------------------------------------------------------
// bf16 MFMA causal flash attention — round 7: largest-first dispatch +
// double-buffered 2-phase pipeline (issue-early / write-late V staging).
// Grid (B*NH, SEQ/64), 256 thr (4 waves x 16 q-rows). KVBLK=64.
// qi = 31 - blockIdx.y  => globally largest-first; XCD = bh%8 stable.
// LDS: Ks[2] 32KB + Vt[2] 32KB + Pl 8KB = 72KB (2 blocks/CU; VGPR was the
// binding limit at 2 anyway). One barrier per KV tile.
// ---------------------------------------------------------------------------
__global__ __launch_bounds__(256) void attn_mfma(const ushort* __restrict__ Q,
                                                 const ushort* __restrict__ K,
                                                 const ushort* __restrict__ V,
                                                 ushort* __restrict__ Out) {
  __shared__ __align__(16) ushort Ks[2][64 * 128];   // [kv][k] swizzled
  __shared__ __align__(16) ushort Vt[2][128 * 64];   // [d][kv] swizzled
  __shared__ __align__(16) ushort Pl[4 * 16 * 64];   // per-wave [q][kv] swizzled
  const int tid  = threadIdx.x;
  const int wave = tid >> 6, lane = tid & 63;
  const int fl = lane & 15, hh = lane >> 4;          // frag row / k-group
  const int bh = blockIdx.x;
  const int qi = (int)gridDim.y - 1 - (int)blockIdx.y;  // largest-first
  const int qs   = qi * 64;
  const int qs_w = qs + wave * 16;
  const ushort* Qb = Q + (size_t)bh * SEQ * HD;
  const ushort* Kb = K + (size_t)bh * SEQ * HD;
  const ushort* Vb = V + (size_t)bh * SEQ * HD;

  // ---- Q fragments in registers: A[row=fl][k=hh*8+j+32kk]
  bf16x8 qa[4];
  {
    const ushort* qrow = Qb + (size_t)(qs_w + fl) * HD + hh * 8;
    #pragma unroll
    for (int kk = 0; kk < 4; ++kk)
      qa[kk] = *(const bf16x8*)(qrow + 32 * kk);
  }

  f32x4 o_acc[8];
  #pragma unroll
  for (int dt = 0; dt < 8; ++dt) o_acc[dt] = (f32x4){0.f, 0.f, 0.f, 0.f};
  float mrow[4] = {-INFINITY, -INFINITY, -INFINITY, -INFINITY};
  float lrow[4] = {0.f, 0.f, 0.f, 0.f};

  ushort* Pw = Pl + wave * (16 * 64);
  uint4 vreg[4];   // staged V rows for next tile (statically indexed)

  // K stage: 16 x 1KB segments; pre-swizzled global source (rule #21)
  auto stageK = [&](int buf, int j0) {
    char* KsC = (char*)Ks[buf];
    #pragma unroll
    for (int i = 0; i < 4; ++i) {
      const int seg = i * 4 + wave;
      const int row = 4 * seg + hh;
      const int gc  = fl ^ (row & 7);
      gload16(Kb + (size_t)(j0 + row) * HD + gc * 8, KsC + seg * 1024);
    }
  };
  auto loadV = [&](int j0) {   // issue-early (T14)
    #pragma unroll
    for (int a = 0; a < 2; ++a) {
      const int idx  = tid + a * 256;
      const int d0   = (idx & 15) * 8;
      const int pair = idx >> 4;
      vreg[2*a]   = *(const uint4*)(Vb + (size_t)(j0 + 2*pair)     * HD + d0);
      vreg[2*a+1] = *(const uint4*)(Vb + (size_t)(j0 + 2*pair + 1) * HD + d0);
    }
  };
  auto writeV = [&](int buf) { // write-late, transposed+swizzled
    char* VtC = (char*)Vt[buf];
    #pragma unroll
    for (int a = 0; a < 2; ++a) {
      const int idx  = tid + a * 256;
      const int d0   = (idx & 15) * 8;
      const int pair = idx >> 4;
      const ushort* u0 = (const ushort*)&vreg[2*a];
      const ushort* u1 = (const ushort*)&vreg[2*a+1];
      #pragma unroll
      for (int j = 0; j < 8; ++j) {
        const int d = d0 + j;
        const int byt = (d * 128 + pair * 4) ^ (((d >> 3) & 7) << 4);
        *(uint*)(VtC + byt) = (uint)u0[j] | ((uint)u1[j] << 16);
      }
    }
  };

  const int nt = qi + 1;
  // ---- prologue: tile 0 into buffer 0
  stageK(0, 0);
  loadV(0);
  writeV(0);
  __syncthreads();

  int cur = 0;
  for (int jt = 0; jt < nt; ++jt) {
    const int j0 = jt * 64;
    const bool more = (jt + 1 < nt);
    if (more) { stageK(cur ^ 1, j0 + 64); loadV(j0 + 64); }  // overlap w/ compute

    char* KsC = (char*)Ks[cur];
    char* VtC = (char*)Vt[cur];

    // ---- QK^T: S[16q x 64kv] per wave
    f32x4 sa[4];
    #pragma unroll
    for (int cc = 0; cc < 4; ++cc) sa[cc] = (f32x4){0.f, 0.f, 0.f, 0.f};
    #pragma unroll
    for (int cc = 0; cc < 4; ++cc) {
      const int row = fl + 16 * cc;
      const int rsw = row & 7;
      #pragma unroll
      for (int kk = 0; kk < 4; ++kk) {
        bf16x8 kb = *(const bf16x8*)(KsC + row * 256 + ((hh + 4 * kk) ^ rsw) * 16);
        sa[cc] = __builtin_amdgcn_mfma_f32_16x16x32_bf16(qa[kk], kb, sa[cc], 0, 0, 0);
      }
    }

    // ---- causal mask (diagonal tile only)
    if (jt == nt - 1) {
      #pragma unroll
      for (int cc = 0; cc < 4; ++cc) {
        const int kv_g = j0 + fl + 16 * cc;
        #pragma unroll
        for (int r = 0; r < 4; ++r)
          if (kv_g > qs_w + 4 * hh + r) sa[cc][r] = -3.0e38f;
      }
    }

    // ---- online softmax (row = 16-lane fl group)
    float tmax[4], psum[4], resc[4];
    #pragma unroll
    for (int r = 0; r < 4; ++r) {
      float t = fmaxf(fmaxf(sa[0][r], sa[1][r]), fmaxf(sa[2][r], sa[3][r]));
      #pragma unroll
      for (int off = 1; off < 16; off <<= 1)
        t = fmaxf(t, __shfl_xor(t, off));
      tmax[r] = t;
    }
    #pragma unroll
    for (int r = 0; r < 4; ++r) {
      const float mnew = fmaxf(mrow[r], tmax[r]);
      resc[r] = __expf(mrow[r] - mnew);
      mrow[r] = mnew;
      float ps = 0.f;
      #pragma unroll
      for (int cc = 0; cc < 4; ++cc) {
        const float p = __expf(sa[cc][r] - mnew);
        sa[cc][r] = p;
        ps += p;
      }
      psum[r] = ps;
    }
    #pragma unroll
    for (int r = 0; r < 4; ++r) {
      float ps = psum[r];
      #pragma unroll
      for (int off = 1; off < 16; off <<= 1)
        ps += __shfl_xor(ps, off);
      lrow[r] = lrow[r] * resc[r] + ps;
    }
    #pragma unroll
    for (int dt = 0; dt < 8; ++dt)
      #pragma unroll
      for (int r = 0; r < 4; ++r) o_acc[dt][r] *= resc[r];

    // ---- P -> bf16 -> per-wave LDS (swizzled: block ^= q&7)
    #pragma unroll
    for (int cc = 0; cc < 4; ++cc) {
      const int kv = fl + 16 * cc;
      #pragma unroll
      for (int r = 0; r < 4; ++r) {
        const int q = 4 * hh + r;
        const int byt = q * 128 + (((kv >> 3) ^ (q & 7)) << 4) + (kv & 7) * 2;
        *(ushort*)((char*)Pw + byt) = f2bf(sa[cc][r]);
      }
    }

    // ---- PV: O[16q x 128d] += P[16 x 64] * V[64 x 128]
    #pragma unroll
    for (int chunk = 0; chunk < 2; ++chunk) {
      bf16x8 pa = *(const bf16x8*)((char*)Pw + fl * 128 +
                                   (((hh + 4 * chunk) ^ (fl & 7)) << 4));
      #pragma unroll
      for (int dt = 0; dt < 8; ++dt) {
        const int d = fl + 16 * dt;
        bf16x8 vbf = *(const bf16x8*)(VtC + ((d * 128 + hh * 16 + 64 * chunk) ^
                                             (((d >> 3) & 7) << 4)));
        o_acc[dt] = __builtin_amdgcn_mfma_f32_16x16x32_bf16(pa, vbf, o_acc[dt], 0, 0, 0);
      }
    }

    if (more) writeV(cur ^ 1);   // vmcnt wait folds here; hidden under compute
    __syncthreads();             // drains gload16 + ds_writes; readers of cur done
    cur ^= 1;
  }

  // ---- epilogue: normalize rows, write bf16 to Out [B*SEQ][HID]
  float inv[4];
  #pragma unroll
  for (int r = 0; r < 4; ++r) inv[r] = 1.0f / lrow[r];
  const int b = bh >> 5, h = bh & 31;
  #pragma unroll
  for (int dt = 0; dt < 8; ++dt) {
    const int d = h * HD + dt * 16 + fl;
    #pragma unroll
    for (int r = 0; r < 4; ++r) {
      const int row_g = qs_w + 4 * hh + r;
      Out[((size_t)(b * SEQ + row_g)) * HID + d] = f2bf(o_acc[dt][r] * inv[r]);
    }
  }
}

// ---------------------------------------------------------------------------
extern "C" void kernel_launch(void* const* d_in, const int* in_sizes, int n_in,
                              void* d_out, int out_size, void* d_ws, size_t ws_size,
                              hipStream_t stream) {
  const int*   positions = (const int*)d_in[0];
  const float* hidden    = (const float*)d_in[1];
  const float* w_qkv     = (const float*)d_in[2];
  const float* b_qkv     = (const float*)d_in[3];
  const float* w_proj    = (const float*)d_in[4];
  float* out = (float*)d_out;

  ushort* ws16 = (ushort*)d_ws;
  ushort* qb = ws16;
  ushort* kb = ws16 + TEN;
  ushort* vb = ws16 + 2 * TEN;
  ushort* wT = ws16 + 3 * TEN;
  ushort* hA = ws16 + 3 * TEN + (size_t)(3 * HID) * HID;

  conv_bf16<<<8192, 256, 0, stream>>>(hidden, hA);
  transp_bf16<<<dim3(3 * HID / 32, HID / 32), 256, 0, stream>>>(w_qkv, wT, HID, 3 * HID);
  gemm_mfma<0><<<dim3(3 * HID / 128, 32), 256, 0, stream>>>(hA, wT, b_qkv, (void*)qb,
                                                            3 * HID, HID);
  rope_kernel<<<32768, 256, 0, stream>>>(qb, kb, positions);
  transp_bf16<<<dim3(HID / 32, HID / 32), 256, 0, stream>>>(w_proj, wT, HID, HID);
  attn_mfma<<<dim3(B_ * NH, SEQ / 64), 256, 0, stream>>>(qb, kb, vb, hA);
  gemm_mfma<1><<<dim3(HID / 128, 32), 256, 0, stream>>>(hA, wT, nullptr, (void*)out,
                                                        HID, HID);
}